// Round 3
// baseline (107.619 us; speedup 1.0000x reference)
//
#include <hip/hip_runtime.h>

// LIF constants (fp32): DT=1e-3, TAU_MEM_INV=200 -> v_decayed = v + 0.2*(i - v)
//                       TAU_SYN_INV=400 -> i_decayed = 0.6*i
// z = heaviside(v_decayed - 1) = (v_decayed > 1)
#define VM_K 0.2f
#define SYN_DECAY 0.6f
#define UNROLL 16

__global__ __launch_bounds__(256) void lif_scan_kernel(
    const float* __restrict__ x, float* __restrict__ out, int N, int T)
{
    int idx = blockIdx.x * blockDim.x + threadIdx.x;
    if (idx >= N) return;

    float v1 = 0.f, i1 = 0.f, v2 = 0.f, i2 = 0.f;

    const float* xp = x + idx;
    float* op = out + idx;

    // T divisible by UNROLL (256 / 16)
    for (int t0 = 0; t0 < T; t0 += UNROLL) {
        float xt[UNROLL];
#pragma unroll
        for (int u = 0; u < UNROLL; ++u)
            xt[u] = xp[(size_t)(t0 + u) * N];   // 16 loads in flight

        float z2v[UNROLL];
#pragma unroll
        for (int u = 0; u < UNROLL; ++u) {
            // layer 1
            float v1d = v1 + VM_K * (i1 - v1);
            float z1  = (v1d > 1.0f) ? 1.f : 0.f;
            v1 = (v1d > 1.0f) ? 0.f : v1d;
            i1 = SYN_DECAY * i1 + xt[u];

            // layer 2 (input = z1)
            float v2d = v2 + VM_K * (i2 - v2);
            float z2  = (v2d > 1.0f) ? 1.f : 0.f;
            v2 = (v2d > 1.0f) ? 0.f : v2d;
            i2 = SYN_DECAY * i2 + z1;

            z2v[u] = z2;
        }

#pragma unroll
        for (int u = 0; u < UNROLL; ++u)
            op[(size_t)(t0 + u) * N] = z2v[u];  // burst stores
    }
}

extern "C" void kernel_launch(void* const* d_in, const int* in_sizes, int n_in,
                              void* d_out, int out_size, void* d_ws, size_t ws_size,
                              hipStream_t stream) {
    const float* x = (const float*)d_in[0];
    float* out = (float*)d_out;

    // x: [T=256, B=16, H=128, W=128] fp32
    const int T = 256;
    const int N = in_sizes[0] / T;   // 262144 spatial elements

    const int block = 256;
    const int grid = (N + block - 1) / block;  // 1024 blocks, 4 waves/SIMD

    lif_scan_kernel<<<grid, block, 0, stream>>>(x, out, N, T);
}

// Round 4
// 98.402 us; speedup vs baseline: 1.0937x; 1.0937x over previous
//
#include <hip/hip_runtime.h>

// LIF constants (fp32): DT=1e-3, TAU_MEM_INV=200 -> v_decayed = v + 0.2*(i - v)
//                       TAU_SYN_INV=400 -> i_decayed = 0.6*i
// z = heaviside(v_decayed - 1) = (v_decayed > 1)
#define VM_K 0.2f
#define SYN_DECAY 0.6f

__global__ __launch_bounds__(256) void lif_scan_kernel(
    const float4* __restrict__ x, float4* __restrict__ out, int N4, int T)
{
    int idx = blockIdx.x * blockDim.x + threadIdx.x;
    if (idx >= N4) return;

    float4 v1 = make_float4(0.f, 0.f, 0.f, 0.f);
    float4 i1 = v1, v2 = v1, i2 = v1;

    const float4* xp = x + idx;
    float4* op = out + idx;

    // Interleaved structure (load -> compute -> store per step), deep unroll so
    // the compiler hoists many independent loads ahead of the serial state chain.
#pragma unroll 8
    for (int t = 0; t < T; ++t) {
        float4 xt = xp[(size_t)t * N4];
        float4 z2;

        {
            float v1d = v1.x + VM_K * (i1.x - v1.x);
            float z1  = (v1d > 1.0f) ? 1.f : 0.f;
            v1.x = (v1d > 1.0f) ? 0.f : v1d;
            i1.x = SYN_DECAY * i1.x + xt.x;
            float v2d = v2.x + VM_K * (i2.x - v2.x);
            z2.x = (v2d > 1.0f) ? 1.f : 0.f;
            v2.x = (v2d > 1.0f) ? 0.f : v2d;
            i2.x = SYN_DECAY * i2.x + z1;
        }
        {
            float v1d = v1.y + VM_K * (i1.y - v1.y);
            float z1  = (v1d > 1.0f) ? 1.f : 0.f;
            v1.y = (v1d > 1.0f) ? 0.f : v1d;
            i1.y = SYN_DECAY * i1.y + xt.y;
            float v2d = v2.y + VM_K * (i2.y - v2.y);
            z2.y = (v2d > 1.0f) ? 1.f : 0.f;
            v2.y = (v2d > 1.0f) ? 0.f : v2d;
            i2.y = SYN_DECAY * i2.y + z1;
        }
        {
            float v1d = v1.z + VM_K * (i1.z - v1.z);
            float z1  = (v1d > 1.0f) ? 1.f : 0.f;
            v1.z = (v1d > 1.0f) ? 0.f : v1d;
            i1.z = SYN_DECAY * i1.z + xt.z;
            float v2d = v2.z + VM_K * (i2.z - v2.z);
            z2.z = (v2d > 1.0f) ? 1.f : 0.f;
            v2.z = (v2d > 1.0f) ? 0.f : v2d;
            i2.z = SYN_DECAY * i2.z + z1;
        }
        {
            float v1d = v1.w + VM_K * (i1.w - v1.w);
            float z1  = (v1d > 1.0f) ? 1.f : 0.f;
            v1.w = (v1d > 1.0f) ? 0.f : v1d;
            i1.w = SYN_DECAY * i1.w + xt.w;
            float v2d = v2.w + VM_K * (i2.w - v2.w);
            z2.w = (v2d > 1.0f) ? 1.f : 0.f;
            v2.w = (v2d > 1.0f) ? 0.f : v2d;
            i2.w = SYN_DECAY * i2.w + z1;
        }

        op[(size_t)t * N4] = z2;
    }
}

extern "C" void kernel_launch(void* const* d_in, const int* in_sizes, int n_in,
                              void* d_out, int out_size, void* d_ws, size_t ws_size,
                              hipStream_t stream) {
    const float* x = (const float*)d_in[0];
    float* out = (float*)d_out;

    // x: [T=256, B=16, H=128, W=128] fp32
    const int T = 256;
    const int N = in_sizes[0] / T;   // 262144 spatial elements
    const int N4 = N / 4;            // 65536

    const int block = 256;
    const int grid = (N4 + block - 1) / block;  // 256 blocks

    lif_scan_kernel<<<grid, block, 0, stream>>>(
        (const float4*)x, (float4*)out, N4, T);
}